// Round 15
// baseline (427.539 us; speedup 1.0000x reference)
//
#include <hip/hip_runtime.h>
#include <hip/hip_bf16.h>
#include <stdint.h>

#define M_ROWS 4096
#define N_REFS 32768
#define DIM    512
#define NSPLIT 32
#define BM     128
#define CHUNK  128
#define SLICE  (N_REFS / NSPLIT)   // 1024
#define NCHUNKS (SLICE / CHUNK)    // 8
#define NKT    (DIM / 128)         // 4 K-tiles of 128 fp8 elems
#define NSTEP  (NCHUNKS * NKT)     // 32 flattened pipeline steps
#define ABUF   16384               // A tile: 128 rows x 128B

typedef __attribute__((ext_vector_type(4))) int   i32x4;
typedef __attribute__((ext_vector_type(8))) int   i32x8;
typedef __attribute__((ext_vector_type(4))) float f32x4;

#define C_L2E2 2.0813689810056077f   // (log2 e)^2: exp(-sqrt(t)) == exp2(-sqrt(C*t))

// fp32 -> OCP e4m3fn, RNE, saturating. Bit-exact, no builtins.
__device__ __forceinline__ uint32_t f32_to_e4m3(float f) {
  uint32_t u = __float_as_uint(f);
  uint32_t s = (u >> 24) & 0x80u;
  float a = fabsf(f);
  if (a > 448.f) a = 448.f;                  // e4m3fn has no inf; saturate
  uint32_t b;
  if (a >= 0.015625f) {                      // normal range (>= 2^-6)
    uint32_t v = __float_as_uint(a);
    v += 0x7FFFFu + ((v >> 20) & 1u);        // RNE at mantissa bit 20
    int e = (int)(v >> 23) - 127;
    uint32_t m = (v >> 20) & 7u;
    b = (uint32_t)((e + 7) << 3) | m;
    if (b > 0x7Eu) b = 0x7Eu;                // clamp to 448
  } else {
    b = (uint32_t)(a * 512.f + 0.5f);        // subnormal grid 2^-9 (m<=8 ok)
  }
  return s | b;
}

// Fused prep (one launch): rows 0..M-1 -> x, rows M.. -> xref.
__global__ void prep_all_fp8(const float* __restrict__ x, const float* __restrict__ xref,
                             uint8_t* __restrict__ xf8, uint8_t* __restrict__ rf8,
                             float* __restrict__ cx2, float* __restrict__ cr2) {
  const int b = blockIdx.x;
  const float* src; uint8_t* dst; float* sq; int row;
  if (b < M_ROWS) { src = x;    dst = xf8; sq = cx2; row = b; }
  else            { src = xref; dst = rf8; sq = cr2; row = b - M_ROWS; }
  int t = threadIdx.x;                       // 256 threads, 2 elems each
  const float2* s = (const float2*)(src + (size_t)row * DIM);
  float2 v = s[t];
  uint32_t p = f32_to_e4m3(v.x) | (f32_to_e4m3(v.y) << 8);
  ((uint16_t*)(dst + (size_t)row * DIM))[t] = (uint16_t)p;
  float ss = v.x * v.x + v.y * v.y;
  #pragma unroll
  for (int d = 32; d >= 1; d >>= 1) ss += __shfl_down(ss, d, 64);
  __shared__ float wsum[4];
  int w = t >> 6, lane = t & 63;
  if (lane == 0) wsum[w] = ss;
  __syncthreads();
  if (t == 0) sq[row] = C_L2E2 * (wsum[0] + wsum[1] + wsum[2] + wsum[3]);
}

// R14 frame (B-direct, A gll-staged) + B REGISTER DOUBLE-BUFFER: B(g+1) is
// loaded into the other bfr set BEFORE STAGE(g+1), so the vmem queue per step
// is [B-next x8, gll x4] and the single end-of-step vmcnt(0)+barrier (needed
// for the LDS swap anyway) completes both. Mid-step: zero vmem waits — the
// current B is already in registers (R14's failure was draining the A-stage
// to use same-step B). LDS ops/wave-step: 12 (vs R12's 24). All bfr indices
// static (g fully unrolled). Occupancy stays 2 waves/SIMD (VGPR+AGPR bound).
__global__ __launch_bounds__(256, 2) void ask_main(
    const uint8_t* __restrict__ xf8, const uint8_t* __restrict__ rf8,
    const float* __restrict__ cx2, const float* __restrict__ cr2,
    const int* __restrict__ y, const int* __restrict__ yref,
    float* __restrict__ totG, float* __restrict__ matchG)
{
  __shared__ unsigned char smem[2 * ABUF];   // A only: [buf][128 x 128B]

  const int tid  = threadIdx.x;
  const int w    = tid >> 6, lane = tid & 63;
  const int wr   = w >> 1,  wc   = w & 1;
  const int l15  = lane & 15, l4 = lane >> 4;

  // XCD-locality swizzle (R14-measured: FETCH 16.7MB): xcd = wg&7, i = wg>>3;
  // nsl = 4*xcd + (i>>5), mtile = i&31 -> one 512KB B-slice x 32 mtiles at a
  // time per XCD, L2-resident. Bijective for 1024 wgs.
  const int wg    = blockIdx.x;
  const int mtile = (wg >> 3) & 31;
  const int nsl   = (wg & 7) * 4 + (wg >> 8);
  const int bm       = mtile * BM;
  const int colstart = nsl * SLICE;

  // A staging (R12-identical, measured conflict-free): srow = w*8 + lane>>3,
  // linear slot q = lane&7; source slot g: e = q^(row&7); g = e<4?2e:2(e&3)+1.
  const int srow = w * 8 + (lane >> 3);
  const int qsl  = lane & 7;
  const int esl  = qsl ^ (srow & 7);
  const int gsl  = (esl < 4) ? (2 * esl) : (2 * (esl & 3) + 1);
  const uint8_t* gA0 = xf8 + (size_t)(bm + srow) * DIM + gsl * 16;

#define GLL(srcp, dstoff)                                                        \
  __builtin_amdgcn_global_load_lds(                                              \
      (const __attribute__((address_space(1))) void*)(srcp),                     \
      (__attribute__((address_space(3))) void*)(smem + (dstoff)), 16, 0, 0)

#define STAGE(gidx)                                                              \
  { const int dk_ = ((gidx) & 3) * 128, b_ = ((gidx) & 1) * ABUF;                \
    _Pragma("unroll")                                                            \
    for (int cc = 0; cc < 4; ++cc)                                               \
      GLL(gA0 + (size_t)cc * 32 * DIM + dk_, b_ + cc * 4096 + w * 1024); }

  // A fragment read slots (zero-conflict pair, measured 0 in R10/R12)
  const int h   = l15 & 7;
  const int sl0 = (l4 ^ h) * 16;
  const int sl1 = sl0 ^ 64;
  int aoff[4];
  #pragma unroll
  for (int i = 0; i < 4; ++i)
    aoff[i] = (wr * 64 + i * 16 + l15) * 128;

  // B fragment row pointers; advance by CHUNK*DIM at each chunk boundary.
  const uint8_t* pB0 = rf8 + (size_t)(colstart + wc * 64 + 0 * 16 + l15) * DIM + l4 * 32;
  const uint8_t* pB1 = rf8 + (size_t)(colstart + wc * 64 + 1 * 16 + l15) * DIM + l4 * 32;
  const uint8_t* pB2 = rf8 + (size_t)(colstart + wc * 64 + 2 * 16 + l15) * DIM + l4 * 32;
  const uint8_t* pB3 = rf8 + (size_t)(colstart + wc * 64 + 3 * 16 + l15) * DIM + l4 * 32;

#define LOADB(dst, dkb)                                                          \
  { i32x4 lo, hi;                                                                \
    lo = *(const i32x4*)(pB0 + (dkb)); hi = *(const i32x4*)(pB0 + (dkb) + 16);   \
    dst[0] = __builtin_shufflevector(lo, hi, 0, 1, 2, 3, 4, 5, 6, 7);            \
    lo = *(const i32x4*)(pB1 + (dkb)); hi = *(const i32x4*)(pB1 + (dkb) + 16);   \
    dst[1] = __builtin_shufflevector(lo, hi, 0, 1, 2, 3, 4, 5, 6, 7);            \
    lo = *(const i32x4*)(pB2 + (dkb)); hi = *(const i32x4*)(pB2 + (dkb) + 16);   \
    dst[2] = __builtin_shufflevector(lo, hi, 0, 1, 2, 3, 4, 5, 6, 7);            \
    lo = *(const i32x4*)(pB3 + (dkb)); hi = *(const i32x4*)(pB3 + (dkb) + 16);   \
    dst[3] = __builtin_shufflevector(lo, hi, 0, 1, 2, 3, 4, 5, 6, 7); }

  // per-block row metadata, hoisted
  float x2v[16]; int yv[16];
  #pragma unroll
  for (int i = 0; i < 16; ++i) {
    int row = bm + wr * 64 + (i >> 2) * 16 + l4 * 4 + (i & 3);
    x2v[i] = cx2[row];
    yv[i]  = y[row];
  }

  float tot[16], mat[16];
  #pragma unroll
  for (int i = 0; i < 16; ++i) { tot[i] = 0.f; mat[i] = 0.f; }

  f32x4 acc[4][4];
  const f32x4 fz = {0.f, 0.f, 0.f, 0.f};
  float r2cP[4]; int clsP[4];                // epilogue metadata, prefetched @kt2
  i32x8 bfr2[2][4];                          // B register double-buffer

  // ---- prologue: B(0) into set 0, stage A(0) ----
  LOADB(bfr2[0], 0);
  STAGE(0);
  asm volatile("s_waitcnt vmcnt(0)" ::: "memory");
  __builtin_amdgcn_s_barrier();

  #pragma unroll
  for (int g = 0; g < NSTEP; ++g) {
    const int kt = g & 3, ch = g >> 2;
    const int cur = g & 1, nxt = cur ^ 1;    // compile-time (g unrolled)
    const int bofs = cur * ABUF;

    if (kt == 3) {                           // next prefetch is next chunk
      pB0 += CHUNK * DIM; pB1 += CHUNK * DIM; pB2 += CHUNK * DIM; pB3 += CHUNK * DIM;
    }
    if (kt == 2) {                           // epilogue metadata for chunk ch
      const int colb = colstart + ch * CHUNK;
      #pragma unroll
      for (int ni = 0; ni < 4; ++ni) {
        int cg = colb + wc * 64 + ni * 16 + l15;
        r2cP[ni] = cr2[cg];
        clsP[ni] = yref[cg];
      }
    }

    // prefetch B(g+1) FIRST (older than stage in the vmcnt queue), then stage
    if (g + 1 < NSTEP) {
      const int dkb1 = ((g + 1) & 3) * 128;
      LOADB(bfr2[nxt], dkb1);
      STAGE(g + 1);
    }

    if (kt == 0) {
      #pragma unroll
      for (int mi = 0; mi < 4; ++mi)
        #pragma unroll
        for (int ni = 0; ni < 4; ++ni) acc[mi][ni] = fz;
    }

    // A fragments from LDS buf; B already in registers — no vmem wait here
    const unsigned char* pS = smem + bofs;
    #pragma unroll
    for (int mi = 0; mi < 4; ++mi) {
      i32x4 lo = *(const i32x4*)(pS + aoff[mi] + sl0);
      i32x4 hi = *(const i32x4*)(pS + aoff[mi] + sl1);
      i32x8 afr = __builtin_shufflevector(lo, hi, 0, 1, 2, 3, 4, 5, 6, 7);
      #pragma unroll
      for (int ni = 0; ni < 4; ++ni)
        acc[mi][ni] = __builtin_amdgcn_mfma_scale_f32_16x16x128_f8f6f4(
            afr, bfr2[cur][ni], acc[mi][ni],
            0, 0,                      // cbsz=fp8(e4m3), blgp=fp8(e4m3)
            0, 0x7F7F7F7F,             // A scales = 1.0 (E8M0 127)
            0, 0x7F7F7F7F);            // B scales = 1.0
    }

    if (kt == 3) {
      // fused epilogue (chunk ch): e = exp2(-sqrt(cx2 + cr2 - 2c*dot));
      // sits between the B/STAGE issue and the drain -> hides their latency.
      #pragma unroll
      for (int mi = 0; mi < 4; ++mi) {
        #pragma unroll
        for (int r = 0; r < 4; ++r) {
          const int gi = mi * 4 + r;
          float xr = x2v[gi];
          int   yy = yv[gi];
          float tsum = 0.f, msum = 0.f;
          #pragma unroll
          for (int ni = 0; ni < 4; ++ni) {
            float t = fmaf(-2.0f * C_L2E2, acc[mi][ni][r], xr + r2cP[ni]);
            t = fmaxf(t, 0.0f);
            float d = __builtin_amdgcn_sqrtf(t);
            float e = __builtin_amdgcn_exp2f(-d);       // neg = free src modifier
            tsum += e;
            msum = fmaf(e, (clsP[ni] == yy) ? 1.0f : 0.0f, msum);
          }
          tot[gi] += tsum;
          mat[gi] += msum;
        }
      }
    }

    // single drain per step: completes B(g+1) regs + A(g+1) LDS writes
    asm volatile("s_waitcnt vmcnt(0)" ::: "memory");
    __builtin_amdgcn_s_barrier();
  }

  // reduce across the 16 lanes (l15) sharing each row, then merge globally
  #pragma unroll
  for (int i = 0; i < 16; ++i) {
    float t = tot[i], m = mat[i];
    #pragma unroll
    for (int d = 1; d <= 8; d <<= 1) {
      t += __shfl_xor(t, d, 64);
      m += __shfl_xor(m, d, 64);
    }
    if (l15 == 0) {
      int row = bm + wr * 64 + (i >> 2) * 16 + l4 * 4 + (i & 3);
      atomicAdd(&totG[row], t);
      atomicAdd(&matchG[row], m);
    }
  }
#undef GLL
#undef STAGE
#undef LOADB
}

__global__ void finalize_loss(const float* __restrict__ totG, const float* __restrict__ matchG,
                              float* __restrict__ out) {
  __shared__ float red[256];
  int t = threadIdx.x;
  float s = 0.f;
  for (int r = t; r < M_ROWS; r += 256)
    s += logf(matchG[r] / totG[r] + 1e-6f);
  red[t] = s;
  __syncthreads();
  for (int off = 128; off >= 1; off >>= 1) {
    if (t < off) red[t] += red[t + off];
    __syncthreads();
  }
  if (t == 0) out[0] = -red[0] / (float)M_ROWS;
}

extern "C" void kernel_launch(void* const* d_in, const int* in_sizes, int n_in,
                              void* d_out, int out_size, void* d_ws, size_t ws_size,
                              hipStream_t stream) {
  const float* x    = (const float*)d_in[0];
  const float* xref = (const float*)d_in[1];
  const int*   y    = (const int*)d_in[2];
  const int*   yref = (const int*)d_in[3];
  float* out = (float*)d_out;

  uint8_t* ws = (uint8_t*)d_ws;
  uint8_t* xf8    = ws;                                 //  2 MB
  uint8_t* rf8    = ws + 2097152;                       // 16 MB
  float*   cx2    = (float*)(ws + 18874368);            // 16 KB (pre-scaled)
  float*   cr2    = (float*)(ws + 18890752);            // 128 KB (pre-scaled)
  float*   totG   = (float*)(ws + 19021824);            // 16 KB
  float*   matchG = (float*)(ws + 19038208);            // 16 KB

  hipMemsetAsync(totG, 0, 2 * M_ROWS * sizeof(float), stream);

  prep_all_fp8<<<M_ROWS + N_REFS, 256, 0, stream>>>(x, xref, xf8, rf8, cx2, cr2);
  ask_main<<<(M_ROWS / BM) * NSPLIT, 256, 0, stream>>>(xf8, rf8, cx2, cr2, y, yref, totG, matchG);
  finalize_loss<<<1, 256, 0, stream>>>(totG, matchG, out);
}